// Round 1
// baseline (247.894 us; speedup 1.0000x reference)
//
#include <hip/hip_runtime.h>

// ---------------- problem constants ----------------
#define Bb 10
#define Cc 3
#define Hh 50
#define Ww 101
#define Kk 4096
#define GRID_CELLS (Bb*Cc*Hh*Ww)   // 151500

// conv1: IC=3 OC=32 k7 s2 p3 : [10,3,50,101] -> [10,32,25,51]
#define C1H 25
#define C1W 51
// pool1: k3 s2 -> [10,32,12,25]
#define P1H 12
#define P1W 25
// conv2: IC=32 OC=64 k5 s1 p2 : -> [10,64,12,25]
// pool2: k2 s2 -> [10,64,6,12]
#define P2H 6
#define P2W 12
// conv3: IC=64 OC=128 k3 s1 p1 : -> [10,128,6,12]
// pool3: k2 s2 -> [10,128,3,6]
#define P3H 3
#define P3W 6

// ---------------- scatter: last-write-wins order index ----------------
__global__ void init_order_kernel(int* __restrict__ order) {
    int t = blockIdx.x * blockDim.x + threadIdx.x;
    if (t < GRID_CELLS) order[t] = -1;
}

__global__ void scatter_kernel(const int* __restrict__ x, int* __restrict__ order) {
    int t = blockIdx.x * blockDim.x + threadIdx.x;
    const int total = Bb * Cc * (Kk + 1);
    if (t >= total) return;
    int k1 = t % (Kk + 1);
    int bc = t / (Kk + 1);
    int col, row;
    if (k1 == 0) { col = 50; row = 48; }  // base fill(48,50) prepended per slice
    else {
        int idx = (bc * Kk + (k1 - 1)) * 2;
        col = x[idx];
        row = x[idx + 1];
    }
    int base = bc * Hh * Ww;
    int o = k1 * 10;
    // 9 neighbor writes (0.5) then center (1.0). off==4 (0,0 neighbor) is always
    // dominated by off==9 of the same point (same cell, higher order) -> skip.
    #pragma unroll
    for (int off = 0; off < 10; ++off) {
        if (off == 4) continue;
        int dr, dc;
        if (off == 9) { dr = 0; dc = 0; }
        else { dr = off / 3 - 1; dc = off % 3 - 1; }
        int cell = base + (row + dr) * Ww + (col + dc);
        atomicMax(&order[cell], o + off);
    }
}

__global__ void grid_fill_kernel(const int* __restrict__ order, float* __restrict__ grid) {
    int t = blockIdx.x * blockDim.x + threadIdx.x;
    if (t >= GRID_CELLS) return;
    int o = order[t];
    grid[t] = (o < 0) ? 0.0f : ((o % 10 == 9) ? 1.0f : 0.5f);
}

// ---------------- generic conv + relu ----------------
template <int IC, int OC, int IH, int IW, int OH, int OW, int KS, int STRIDE, int PAD>
__global__ void conv_relu_kernel(const float* __restrict__ in, const float* __restrict__ w,
                                 const float* __restrict__ bias, float* __restrict__ out) {
    int t = blockIdx.x * blockDim.x + threadIdx.x;
    if (t >= Bb * OC * OH * OW) return;
    int ow = t % OW; int tmp = t / OW;
    int oh = tmp % OH; tmp /= OH;
    int oc = tmp % OC; int b = tmp / OC;
    float s = bias[oc];
    int ih0 = oh * STRIDE - PAD;
    int iw0 = ow * STRIDE - PAD;
    for (int ic = 0; ic < IC; ++ic) {
        const float* ip = in + (b * IC + ic) * IH * IW;
        const float* wp = w + (oc * IC + ic) * KS * KS;
        #pragma unroll
        for (int kh = 0; kh < KS; ++kh) {
            int ih = ih0 + kh;
            if (ih < 0 || ih >= IH) continue;
            #pragma unroll
            for (int kw = 0; kw < KS; ++kw) {
                int iw = iw0 + kw;
                if (iw < 0 || iw >= IW) continue;
                s += ip[ih * IW + iw] * wp[kh * KS + kw];
            }
        }
    }
    out[t] = fmaxf(s, 0.0f);
}

// ---------------- generic maxpool (stride 2, VALID) ----------------
template <int CH, int IH, int IW, int OH, int OW, int KS>
__global__ void maxpool_kernel(const float* __restrict__ in, float* __restrict__ out) {
    int t = blockIdx.x * blockDim.x + threadIdx.x;
    if (t >= Bb * CH * OH * OW) return;
    int ow = t % OW; int tmp = t / OW;
    int oh = tmp % OH; tmp /= OH;
    int c = tmp % CH; int b = tmp / CH;
    const float* ip = in + (b * CH + c) * IH * IW;
    float m = -INFINITY;
    #pragma unroll
    for (int kh = 0; kh < KS; ++kh)
        #pragma unroll
        for (int kw = 0; kw < KS; ++kw)
            m = fmaxf(m, ip[(oh * 2 + kh) * IW + (ow * 2 + kw)]);
    out[t] = m;
}

// ---------------- head: global mean + fc1(relu) + fc2 ----------------
__global__ void head_kernel(const float* __restrict__ p3, const float* __restrict__ wl1,
                            const float* __restrict__ bl1, const float* __restrict__ wl2,
                            const float* __restrict__ bl2, float* __restrict__ out) {
    int b = blockIdx.x;       // 10 blocks
    int c = threadIdx.x;      // 128 threads
    __shared__ float feat[128];
    __shared__ float h2[128];
    const float* p = p3 + (b * 128 + c) * (P3H * P3W);
    float s = 0.0f;
    #pragma unroll
    for (int i = 0; i < P3H * P3W; ++i) s += p[i];
    feat[c] = s * (1.0f / (P3H * P3W));
    __syncthreads();
    float a = bl1[c];
    #pragma unroll 8
    for (int k = 0; k < 128; ++k) a += feat[k] * wl1[c * 128 + k];
    h2[c] = fmaxf(a, 0.0f);
    __syncthreads();
    if (c < 5) {
        float a2 = bl2[c];
        #pragma unroll 8
        for (int k = 0; k < 128; ++k) a2 += h2[k] * wl2[c * 128 + k];
        out[b * 5 + c] = a2;
    }
}

// ---------------- launch ----------------
extern "C" void kernel_launch(void* const* d_in, const int* in_sizes, int n_in,
                              void* d_out, int out_size, void* d_ws, size_t ws_size,
                              hipStream_t stream) {
    const int*   x   = (const int*)d_in[0];
    const float* w1  = (const float*)d_in[1];
    const float* b1  = (const float*)d_in[2];
    const float* w2  = (const float*)d_in[3];
    const float* b2  = (const float*)d_in[4];
    const float* w3  = (const float*)d_in[5];
    const float* b3  = (const float*)d_in[6];
    const float* wl1 = (const float*)d_in[7];
    const float* bl1 = (const float*)d_in[8];
    const float* wl2 = (const float*)d_in[9];
    const float* bl2 = (const float*)d_in[10];
    float* out = (float*)d_out;

    // workspace layout (bytes), with lifetime-based aliasing:
    //   regionConv (max conv out = 408000 floats; also holds `order` early, lifetimes disjoint)
    //   regionGrid (151500 floats)
    //   regionPool (max pool out = 96000 floats)
    char* ws = (char*)d_ws;
    const size_t CONV_ELEMS = 408000;            // c1: 10*32*25*51 (largest)
    const size_t GRID_ELEMS = GRID_CELLS;        // 151500
    int*   order = (int*)ws;                     // aliases conv region (dead before conv1 writes)
    float* convb = (float*)ws;                   // c1 / c2 / c3 (sequential lifetimes)
    float* grid  = (float*)(ws + CONV_ELEMS * 4);
    float* poolb = (float*)(ws + (CONV_ELEMS + GRID_ELEMS) * 4);  // p1 / p2 / p3

    const int T = 256;
    // 1. order = -1
    init_order_kernel<<<(GRID_CELLS + T - 1) / T, T, 0, stream>>>(order);
    // 2. scatter atomicMax
    {
        int total = Bb * Cc * (Kk + 1);
        scatter_kernel<<<(total + T - 1) / T, T, 0, stream>>>(x, order);
    }
    // 3. decode order -> grid
    grid_fill_kernel<<<(GRID_CELLS + T - 1) / T, T, 0, stream>>>(order, grid);
    // 4. conv1 + relu : grid -> convb  [10,32,25,51]
    {
        int n = Bb * 32 * C1H * C1W;
        conv_relu_kernel<3, 32, Hh, Ww, C1H, C1W, 7, 2, 3>
            <<<(n + T - 1) / T, T, 0, stream>>>(grid, w1, b1, convb);
    }
    // 5. pool1 : convb -> poolb  [10,32,12,25]
    {
        int n = Bb * 32 * P1H * P1W;
        maxpool_kernel<32, C1H, C1W, P1H, P1W, 3>
            <<<(n + T - 1) / T, T, 0, stream>>>(convb, poolb);
    }
    // 6. conv2 + relu : poolb -> convb  [10,64,12,25]
    {
        int n = Bb * 64 * P1H * P1W;
        conv_relu_kernel<32, 64, P1H, P1W, P1H, P1W, 5, 1, 2>
            <<<(n + T - 1) / T, T, 0, stream>>>(poolb, w2, b2, convb);
    }
    // 7. pool2 : convb -> poolb  [10,64,6,12]
    {
        int n = Bb * 64 * P2H * P2W;
        maxpool_kernel<64, P1H, P1W, P2H, P2W, 2>
            <<<(n + T - 1) / T, T, 0, stream>>>(convb, poolb);
    }
    // 8. conv3 + relu : poolb -> convb  [10,128,6,12]
    {
        int n = Bb * 128 * P2H * P2W;
        conv_relu_kernel<64, 128, P2H, P2W, P2H, P2W, 3, 1, 1>
            <<<(n + T - 1) / T, T, 0, stream>>>(poolb, w3, b3, convb);
    }
    // 9. pool3 : convb -> poolb  [10,128,3,6]
    {
        int n = Bb * 128 * P3H * P3W;
        maxpool_kernel<128, P2H, P2W, P3H, P3W, 2>
            <<<(n + T - 1) / T, T, 0, stream>>>(convb, poolb);
    }
    // 10. head : poolb -> out [10,5]
    head_kernel<<<Bb, 128, 0, stream>>>(poolb, wl1, bl1, wl2, bl2, out);
}

// Round 2
// 149.666 us; speedup vs baseline: 1.6563x; 1.6563x over previous
//
#include <hip/hip_runtime.h>

// ---------------- problem constants ----------------
#define Bb 10
#define Hh 50
#define Ww 101
#define Kk 4096
#define GRID_CELLS (Bb*3*Hh*Ww)   // 151500

// conv1: IC=3 OC=32 k7 s2 p3 : [10,3,50,101] -> [10,32,25,51]
// pool1: k3 s2 -> [10,32,12,25]
// conv2: IC=32 OC=64 k5 s1 p2 -> [10,64,12,25]; pool2 k2 s2 -> [10,64,6,12]
// conv3: IC=64 OC=128 k3 s1 p1 -> [10,128,6,12]; pool3 k2 s2 -> [10,128,3,6]

// ---------------- scatter: last-write-wins order index ----------------
__global__ void scatter_kernel(const int* __restrict__ x, int* __restrict__ order) {
    int t = blockIdx.x * blockDim.x + threadIdx.x;
    const int total = Bb * 3 * (Kk + 1);
    if (t >= total) return;
    int k1 = t % (Kk + 1);
    int bc = t / (Kk + 1);
    int col, row;
    if (k1 == 0) { col = 50; row = 48; }
    else {
        int idx = (bc * Kk + (k1 - 1)) * 2;
        col = x[idx];
        row = x[idx + 1];
    }
    int base = bc * Hh * Ww;
    int o = k1 * 10;
    // 9 neighbors (0.5) then center (1.0); off==4 dominated by off==9 -> skip
    #pragma unroll
    for (int off = 0; off < 10; ++off) {
        if (off == 4) continue;
        int dr, dc;
        if (off == 9) { dr = 0; dc = 0; }
        else { dr = off / 3 - 1; dc = off % 3 - 1; }
        atomicMax(&order[base + (row + dr) * Ww + (col + dc)], o + off);
    }
}

__device__ __forceinline__ float decode_order(int o) {
    return (o < 0) ? 0.0f : ((o % 10 == 9) ? 1.0f : 0.5f);
}

// ---------------- conv1: order -> [10,32,25,51], per-ic padded LDS ----------------
// pad=3: lds[56][109] per ic (24.4 KB). 21 blocks/b; thread = (ocpair16, oh25, owt13), 8 accs.
__global__ void conv1_kernel(const int* __restrict__ order, const float* __restrict__ w1,
                             const float* __restrict__ b1, float* __restrict__ out) {
    __shared__ float lds[56 * 109];
    int blk = blockIdx.x;
    int b = blk / 21;
    int tid = threadIdx.x;
    int u = (blk % 21) * 256 + tid;
    bool active = u < 5200;
    int ocpair = u / 325, rem = u % 325;
    int oh = rem / 13, owt = rem % 13;
    int oc0 = ocpair * 2;
    int ow0 = owt * 4;
    float acc0[4] = {0.f, 0.f, 0.f, 0.f};
    float acc1[4] = {0.f, 0.f, 0.f, 0.f};

    for (int ic = 0; ic < 3; ++ic) {
        for (int i = tid; i < 56 * 109; i += 256) {
            int r = i / 109, c = i % 109;
            int gr = r - 3, gc = c - 3;
            float v = 0.f;
            if (gr >= 0 && gr < Hh && gc >= 0 && gc < Ww)
                v = decode_order(order[((b * 3 + ic) * Hh + gr) * Ww + gc]);
            lds[i] = v;
        }
        __syncthreads();
        if (active) {
            const float* wp0 = w1 + (oc0 * 3 + ic) * 49;
            const float* wp1 = w1 + ((oc0 + 1) * 3 + ic) * 49;
            #pragma unroll
            for (int kh = 0; kh < 7; ++kh) {
                const float* lr = lds + (2 * oh + kh) * 109 + 2 * ow0;
                float s[13];
                #pragma unroll
                for (int k = 0; k < 13; ++k) s[k] = lr[k];
                float wa[7], wb_[7];
                #pragma unroll
                for (int k = 0; k < 7; ++k) { wa[k] = wp0[kh * 7 + k]; wb_[k] = wp1[kh * 7 + k]; }
                #pragma unroll
                for (int kw = 0; kw < 7; ++kw)
                    #pragma unroll
                    for (int j = 0; j < 4; ++j) {
                        acc0[j] += s[2 * j + kw] * wa[kw];
                        acc1[j] += s[2 * j + kw] * wb_[kw];
                    }
            }
        }
        __syncthreads();
    }
    if (active) {
        float bia0 = b1[oc0], bia1 = b1[oc0 + 1];
        #pragma unroll
        for (int j = 0; j < 4; ++j) {
            int ow = ow0 + j;
            if (ow < 51) {
                out[((b * 32 + oc0) * 25 + oh) * 51 + ow] = fmaxf(acc0[j] + bia0, 0.f);
                out[((b * 32 + oc0 + 1) * 25 + oh) * 51 + ow] = fmaxf(acc1[j] + bia1, 0.f);
            }
        }
    }
}

// ---------------- pool1: [10,32,25,51] k3 s2 -> [10,32,12,25] ----------------
__global__ void pool1_kernel(const float* __restrict__ in, float* __restrict__ out) {
    int t = blockIdx.x * blockDim.x + threadIdx.x;
    if (t >= 96000) return;
    int pw = t % 25, tmp = t / 25;
    int ph = tmp % 12, bc = tmp / 12;   // bc over b*32+c
    const float* ip = in + (bc * 25 + 2 * ph) * 51 + 2 * pw;
    float m = -INFINITY;
    #pragma unroll
    for (int r = 0; r < 3; ++r)
        #pragma unroll
        for (int c = 0; c < 3; ++c)
            m = fmaxf(m, ip[r * 51 + c]);
    out[t] = m;
}

// ---------------- conv2+pool2 fused: p1 -> [10,64,6,12] ----------------
// full padded input per b in LDS: [32][16][29] = 58 KB. 18 blocks/b, thread=(oc64,ph6,pw12).
__global__ void conv2p2_kernel(const float* __restrict__ p1, const float* __restrict__ w2,
                               const float* __restrict__ b2, float* __restrict__ p2) {
    __shared__ float lds[32 * 16 * 29];
    int blk = blockIdx.x;
    int b = blk / 18;
    int tid = threadIdx.x;
    int u = (blk % 18) * 256 + tid;   // < 4608 always
    for (int i = tid; i < 32 * 16 * 29; i += 256) {
        int ic = i / 464, rem = i % 464;
        int r = rem / 29, c = rem % 29;
        int gr = r - 2, gc = c - 2;
        float v = 0.f;
        if (gr >= 0 && gr < 12 && gc >= 0 && gc < 25)
            v = p1[((b * 32 + ic) * 12 + gr) * 25 + gc];
        lds[i] = v;
    }
    __syncthreads();
    int pw = u % 12, ph = (u / 12) % 6, oc = u / 72;
    float acc[2][2] = {{0.f, 0.f}, {0.f, 0.f}};
    const float* wbase = w2 + oc * 32 * 25;
    const float* lbase = lds + (2 * ph) * 29 + 2 * pw;
    for (int ic = 0; ic < 32; ++ic) {
        float inr[6][6];
        const float* lp = lbase + ic * 464;
        #pragma unroll
        for (int r = 0; r < 6; ++r)
            #pragma unroll
            for (int c = 0; c < 6; ++c)
                inr[r][c] = lp[r * 29 + c];
        const float* wp = wbase + ic * 25;
        float wr[25];
        #pragma unroll
        for (int k = 0; k < 25; ++k) wr[k] = wp[k];
        #pragma unroll
        for (int kh = 0; kh < 5; ++kh)
            #pragma unroll
            for (int kw = 0; kw < 5; ++kw)
                #pragma unroll
                for (int dy = 0; dy < 2; ++dy)
                    #pragma unroll
                    for (int dx = 0; dx < 2; ++dx)
                        acc[dy][dx] += inr[dy + kh][dx + kw] * wr[kh * 5 + kw];
    }
    float bia = b2[oc];
    float m = fmaxf(fmaxf(fmaxf(acc[0][0], acc[0][1]), fmaxf(acc[1][0], acc[1][1])) + bia, 0.f);
    p2[((b * 64 + oc) * 6 + ph) * 12 + pw] = m;
}

// ---------------- conv3+pool3 fused: p2 -> [10,128,3,6] ----------------
// padded input per b in LDS: [64][8][14] = 28.7 KB. 9 blocks/b, thread=(oc128,ph3,pw6).
__global__ void conv3p3_kernel(const float* __restrict__ p2, const float* __restrict__ w3,
                               const float* __restrict__ b3, float* __restrict__ p3) {
    __shared__ float lds[64 * 8 * 14];
    int blk = blockIdx.x;
    int b = blk / 9;
    int tid = threadIdx.x;
    int u = (blk % 9) * 256 + tid;   // < 2304 always
    for (int i = tid; i < 64 * 8 * 14; i += 256) {
        int ic = i / 112, rem = i % 112;
        int r = rem / 14, c = rem % 14;
        int gr = r - 1, gc = c - 1;
        float v = 0.f;
        if (gr >= 0 && gr < 6 && gc >= 0 && gc < 12)
            v = p2[((b * 64 + ic) * 6 + gr) * 12 + gc];
        lds[i] = v;
    }
    __syncthreads();
    int pw = u % 6, ph = (u / 6) % 3, oc = u / 18;
    float acc[2][2] = {{0.f, 0.f}, {0.f, 0.f}};
    const float* wbase = w3 + oc * 64 * 9;
    const float* lbase = lds + (2 * ph) * 14 + 2 * pw;
    for (int ic = 0; ic < 64; ++ic) {
        float inr[4][4];
        const float* lp = lbase + ic * 112;
        #pragma unroll
        for (int r = 0; r < 4; ++r)
            #pragma unroll
            for (int c = 0; c < 4; ++c)
                inr[r][c] = lp[r * 14 + c];
        const float* wp = wbase + ic * 9;
        float wr[9];
        #pragma unroll
        for (int k = 0; k < 9; ++k) wr[k] = wp[k];
        #pragma unroll
        for (int kh = 0; kh < 3; ++kh)
            #pragma unroll
            for (int kw = 0; kw < 3; ++kw)
                #pragma unroll
                for (int dy = 0; dy < 2; ++dy)
                    #pragma unroll
                    for (int dx = 0; dx < 2; ++dx)
                        acc[dy][dx] += inr[dy + kh][dx + kw] * wr[kh * 3 + kw];
    }
    float bia = b3[oc];
    float m = fmaxf(fmaxf(fmaxf(acc[0][0], acc[0][1]), fmaxf(acc[1][0], acc[1][1])) + bia, 0.f);
    p3[((b * 128 + oc) * 3 + ph) * 6 + pw] = m;
}

// ---------------- head: global mean + fc1(relu) + fc2 ----------------
__global__ void head_kernel(const float* __restrict__ p3, const float* __restrict__ wl1,
                            const float* __restrict__ bl1, const float* __restrict__ wl2,
                            const float* __restrict__ bl2, float* __restrict__ out) {
    int b = blockIdx.x;
    int c = threadIdx.x;
    __shared__ float feat[128];
    __shared__ float h2[128];
    const float* p = p3 + (b * 128 + c) * 18;
    float s = 0.0f;
    #pragma unroll
    for (int i = 0; i < 18; ++i) s += p[i];
    feat[c] = s * (1.0f / 18.0f);
    __syncthreads();
    float a = bl1[c];
    #pragma unroll 8
    for (int k = 0; k < 128; ++k) a += feat[k] * wl1[c * 128 + k];
    h2[c] = fmaxf(a, 0.0f);
    __syncthreads();
    if (c < 5) {
        float a2 = bl2[c];
        #pragma unroll 8
        for (int k = 0; k < 128; ++k) a2 += h2[k] * wl2[c * 128 + k];
        out[b * 5 + c] = a2;
    }
}

// ---------------- launch ----------------
extern "C" void kernel_launch(void* const* d_in, const int* in_sizes, int n_in,
                              void* d_out, int out_size, void* d_ws, size_t ws_size,
                              hipStream_t stream) {
    const int*   x   = (const int*)d_in[0];
    const float* w1  = (const float*)d_in[1];
    const float* b1  = (const float*)d_in[2];
    const float* w2  = (const float*)d_in[3];
    const float* b2  = (const float*)d_in[4];
    const float* w3  = (const float*)d_in[5];
    const float* b3  = (const float*)d_in[6];
    const float* wl1 = (const float*)d_in[7];
    const float* bl1 = (const float*)d_in[8];
    const float* wl2 = (const float*)d_in[9];
    const float* bl2 = (const float*)d_in[10];
    float* out = (float*)d_out;

    // workspace (lifetime-aliased, 2.622 MB total == round-0 footprint):
    //   [0, 606000)            order (int)     ... later p2 (184.3 KB)
    //   [606000, 2238000)      conv1out        ... later p3 (92.2 KB)
    //   [2238000, 2622000)     p1
    char* ws = (char*)d_ws;
    int*   order    = (int*)ws;
    float* conv1out = (float*)(ws + 606000);
    float* p1       = (float*)(ws + 2238000);
    float* p2       = (float*)ws;              // order dead after conv1
    float* p3       = (float*)(ws + 606000);   // conv1out dead after pool1

    hipMemsetAsync(order, 0xFF, GRID_CELLS * sizeof(int), stream);   // order = -1
    {
        int total = Bb * 3 * (Kk + 1);
        scatter_kernel<<<(total + 255) / 256, 256, 0, stream>>>(x, order);
    }
    conv1_kernel<<<Bb * 21, 256, 0, stream>>>(order, w1, b1, conv1out);
    pool1_kernel<<<(96000 + 255) / 256, 256, 0, stream>>>(conv1out, p1);
    conv2p2_kernel<<<Bb * 18, 256, 0, stream>>>(p1, w2, b2, p2);
    conv3p3_kernel<<<Bb * 9, 256, 0, stream>>>(p2, w3, b3, p3);
    head_kernel<<<Bb, 128, 0, stream>>>(p3, wl1, bl1, wl2, bl2, out);
}

// Round 3
// 104.622 us; speedup vs baseline: 2.3694x; 1.4305x over previous
//
#include <hip/hip_runtime.h>

// ---------------- problem constants ----------------
#define Bb 10
#define Hh 50
#define Ww 101
#define Kk 4096
#define SLICE (Hh*Ww)             // 5050
#define GRID_CELLS (Bb*3*SLICE)   // 151500

// conv1: IC=3 OC=32 k7 s2 p3 : [10,3,50,101] -> [10,32,25,51]; pool1 k3 s2 -> [10,32,12,25]
// conv2: IC=32 OC=64 k5 s1 p2 -> [10,64,12,25]; pool2 k2 s2 -> [10,64,6,12]
// conv3: IC=64 OC=128 k3 s1 p1 -> [10,128,6,12]; pool3 k2 s2 -> [10,128,3,6]

// ---------------- fused scatter + dilate + decode ----------------
// One block per (b,c) slice. lastK[cell] = max point-index whose CENTER is at cell
// (LDS atomicMax, 1 per point). Final value: M = 3x3 max-dilation of lastK;
// cell = 0 if M<0, 1.0 if lastK==M (center wrote last; ties->center), else 0.5.
__global__ void scatter_grid_kernel(const int* __restrict__ x, float* __restrict__ grid) {
    __shared__ int lastK[SLICE];
    int bc = blockIdx.x;
    int tid = threadIdx.x;
    for (int i = tid; i < SLICE; i += 256) lastK[i] = -1;
    __syncthreads();
    const int2* xp = (const int2*)(x + bc * Kk * 2);   // (col,row) pairs
    for (int k = tid; k < Kk + 1; k += 256) {
        int col, row;
        if (k == 0) { col = 50; row = 48; }            // prepended base fill
        else { int2 p = xp[k - 1]; col = p.x; row = p.y; }
        atomicMax(&lastK[row * Ww + col], k);
    }
    __syncthreads();
    float* g = grid + bc * SLICE;
    for (int i = tid; i < SLICE; i += 256) {
        int r = i / Ww, c = i % Ww;
        int m = -1;
        #pragma unroll
        for (int dr = -1; dr <= 1; ++dr) {
            int rr = r + dr;
            if (rr < 0 || rr >= Hh) continue;
            #pragma unroll
            for (int dc = -1; dc <= 1; ++dc) {
                int cc = c + dc;
                if (cc < 0 || cc >= Ww) continue;
                m = max(m, lastK[rr * Ww + cc]);
            }
        }
        g[i] = (m < 0) ? 0.0f : ((lastK[i] == m) ? 1.0f : 0.5f);
    }
}

// ---------------- conv1 + pool1 fused ----------------
// block = (b, ocpair): 160 blocks, 384 threads. Grid slice per ic staged in padded
// LDS [56][109]; conv out (2 oc x 25 x 51) accumulated in regs, dumped to LDS, pooled.
__global__ void conv1p1_kernel(const float* __restrict__ grid, const float* __restrict__ w1,
                               const float* __restrict__ b1, float* __restrict__ p1) {
    __shared__ float lds[56 * 109];
    __shared__ float ctile[2 * 25 * 52];   // stride 52 (pad)
    int blk = blockIdx.x;
    int b = blk / 16, ocpair = blk % 16;
    int oc0 = ocpair * 2;
    int tid = threadIdx.x;
    bool active = tid < 325;               // (oh 25) x (owt 13)
    int oh = tid / 13, owt = tid % 13;
    int ow0 = owt * 4;
    float acc0[4] = {0.f, 0.f, 0.f, 0.f};
    float acc1[4] = {0.f, 0.f, 0.f, 0.f};

    for (int ic = 0; ic < 3; ++ic) {
        for (int i = tid; i < 56 * 109; i += 384) {
            int r = i / 109, c = i % 109;
            int gr = r - 3, gc = c - 3;
            float v = 0.f;
            if (gr >= 0 && gr < Hh && gc >= 0 && gc < Ww)
                v = grid[((b * 3 + ic) * Hh + gr) * Ww + gc];
            lds[i] = v;
        }
        __syncthreads();
        if (active) {
            const float* wp0 = w1 + (oc0 * 3 + ic) * 49;
            const float* wp1 = w1 + ((oc0 + 1) * 3 + ic) * 49;
            #pragma unroll
            for (int kh = 0; kh < 7; ++kh) {
                const float* lr = lds + (2 * oh + kh) * 109 + 2 * ow0;
                float s[13];
                #pragma unroll
                for (int k = 0; k < 13; ++k) s[k] = lr[k];
                float wa[7], wb_[7];
                #pragma unroll
                for (int k = 0; k < 7; ++k) { wa[k] = wp0[kh * 7 + k]; wb_[k] = wp1[kh * 7 + k]; }
                #pragma unroll
                for (int kw = 0; kw < 7; ++kw)
                    #pragma unroll
                    for (int j = 0; j < 4; ++j) {
                        acc0[j] += s[2 * j + kw] * wa[kw];
                        acc1[j] += s[2 * j + kw] * wb_[kw];
                    }
            }
        }
        __syncthreads();
    }
    if (active) {
        float bia0 = b1[oc0], bia1 = b1[oc0 + 1];
        #pragma unroll
        for (int j = 0; j < 4; ++j) {
            int ow = ow0 + j;
            if (ow < 51) {
                ctile[(0 * 25 + oh) * 52 + ow] = fmaxf(acc0[j] + bia0, 0.f);
                ctile[(1 * 25 + oh) * 52 + ow] = fmaxf(acc1[j] + bia1, 0.f);
            }
        }
    }
    __syncthreads();
    // pool: 2 oc x 12 x 25 = 600 outputs
    for (int pu = tid; pu < 600; pu += 384) {
        int oc = pu / 300, rem = pu % 300;
        int ph = rem / 25, pw = rem % 25;
        const float* cp = ctile + (oc * 25 + 2 * ph) * 52 + 2 * pw;
        float m = -INFINITY;
        #pragma unroll
        for (int r = 0; r < 3; ++r)
            #pragma unroll
            for (int c = 0; c < 3; ++c)
                m = fmaxf(m, cp[r * 52 + c]);
        p1[((b * 32 + oc0 + oc) * 12 + ph) * 25 + pw] = m;
    }
}

// ---------------- conv2+pool2 fused: p1 -> [10,64,6,12] ----------------
__global__ void conv2p2_kernel(const float* __restrict__ p1, const float* __restrict__ w2,
                               const float* __restrict__ b2, float* __restrict__ p2) {
    __shared__ float lds[32 * 16 * 29];
    int blk = blockIdx.x;
    int b = blk / 18;
    int tid = threadIdx.x;
    int u = (blk % 18) * 256 + tid;   // < 4608 always
    for (int i = tid; i < 32 * 16 * 29; i += 256) {
        int ic = i / 464, rem = i % 464;
        int r = rem / 29, c = rem % 29;
        int gr = r - 2, gc = c - 2;
        float v = 0.f;
        if (gr >= 0 && gr < 12 && gc >= 0 && gc < 25)
            v = p1[((b * 32 + ic) * 12 + gr) * 25 + gc];
        lds[i] = v;
    }
    __syncthreads();
    int pw = u % 12, ph = (u / 12) % 6, oc = u / 72;
    float acc[2][2] = {{0.f, 0.f}, {0.f, 0.f}};
    const float* wbase = w2 + oc * 32 * 25;
    const float* lbase = lds + (2 * ph) * 29 + 2 * pw;
    for (int ic = 0; ic < 32; ++ic) {
        float inr[6][6];
        const float* lp = lbase + ic * 464;
        #pragma unroll
        for (int r = 0; r < 6; ++r)
            #pragma unroll
            for (int c = 0; c < 6; ++c)
                inr[r][c] = lp[r * 29 + c];
        const float* wp = wbase + ic * 25;
        float wr[25];
        #pragma unroll
        for (int k = 0; k < 25; ++k) wr[k] = wp[k];
        #pragma unroll
        for (int kh = 0; kh < 5; ++kh)
            #pragma unroll
            for (int kw = 0; kw < 5; ++kw)
                #pragma unroll
                for (int dy = 0; dy < 2; ++dy)
                    #pragma unroll
                    for (int dx = 0; dx < 2; ++dx)
                        acc[dy][dx] += inr[dy + kh][dx + kw] * wr[kh * 5 + kw];
    }
    float bia = b2[oc];
    float m = fmaxf(fmaxf(fmaxf(acc[0][0], acc[0][1]), fmaxf(acc[1][0], acc[1][1])) + bia, 0.f);
    p2[((b * 64 + oc) * 6 + ph) * 12 + pw] = m;
}

// ---------------- conv3+pool3 fused: p2 -> [10,128,3,6] ----------------
__global__ void conv3p3_kernel(const float* __restrict__ p2, const float* __restrict__ w3,
                               const float* __restrict__ b3, float* __restrict__ p3) {
    __shared__ float lds[64 * 8 * 14];
    int blk = blockIdx.x;
    int b = blk / 9;
    int tid = threadIdx.x;
    int u = (blk % 9) * 256 + tid;   // < 2304 always
    for (int i = tid; i < 64 * 8 * 14; i += 256) {
        int ic = i / 112, rem = i % 112;
        int r = rem / 14, c = rem % 14;
        int gr = r - 1, gc = c - 1;
        float v = 0.f;
        if (gr >= 0 && gr < 6 && gc >= 0 && gc < 12)
            v = p2[((b * 64 + ic) * 6 + gr) * 12 + gc];
        lds[i] = v;
    }
    __syncthreads();
    int pw = u % 6, ph = (u / 6) % 3, oc = u / 18;
    float acc[2][2] = {{0.f, 0.f}, {0.f, 0.f}};
    const float* wbase = w3 + oc * 64 * 9;
    const float* lbase = lds + (2 * ph) * 14 + 2 * pw;
    for (int ic = 0; ic < 64; ++ic) {
        float inr[4][4];
        const float* lp = lbase + ic * 112;
        #pragma unroll
        for (int r = 0; r < 4; ++r)
            #pragma unroll
            for (int c = 0; c < 4; ++c)
                inr[r][c] = lp[r * 14 + c];
        const float* wp = wbase + ic * 9;
        float wr[9];
        #pragma unroll
        for (int k = 0; k < 9; ++k) wr[k] = wp[k];
        #pragma unroll
        for (int kh = 0; kh < 3; ++kh)
            #pragma unroll
            for (int kw = 0; kw < 3; ++kw)
                #pragma unroll
                for (int dy = 0; dy < 2; ++dy)
                    #pragma unroll
                    for (int dx = 0; dx < 2; ++dx)
                        acc[dy][dx] += inr[dy + kh][dx + kw] * wr[kh * 3 + kw];
    }
    float bia = b3[oc];
    float m = fmaxf(fmaxf(fmaxf(acc[0][0], acc[0][1]), fmaxf(acc[1][0], acc[1][1])) + bia, 0.f);
    p3[((b * 128 + oc) * 3 + ph) * 6 + pw] = m;
}

// ---------------- head: global mean + fc1(relu) + fc2, float4 weight loads ----------------
__global__ void head_kernel(const float* __restrict__ p3, const float* __restrict__ wl1,
                            const float* __restrict__ bl1, const float* __restrict__ wl2,
                            const float* __restrict__ bl2, float* __restrict__ out) {
    int b = blockIdx.x;
    int c = threadIdx.x;
    __shared__ float feat[128];
    __shared__ float h2[128];
    const float* p = p3 + (b * 128 + c) * 18;
    float s = 0.0f;
    #pragma unroll
    for (int i = 0; i < 18; ++i) s += p[i];
    feat[c] = s * (1.0f / 18.0f);
    __syncthreads();
    float a = bl1[c];
    const float4* wr = (const float4*)(wl1 + c * 128);
    #pragma unroll 8
    for (int k4 = 0; k4 < 32; ++k4) {
        float4 w = wr[k4];
        a += feat[4 * k4] * w.x + feat[4 * k4 + 1] * w.y + feat[4 * k4 + 2] * w.z + feat[4 * k4 + 3] * w.w;
    }
    h2[c] = fmaxf(a, 0.0f);
    __syncthreads();
    if (c < 5) {
        float a2 = bl2[c];
        const float4* wr2 = (const float4*)(wl2 + c * 128);
        #pragma unroll 8
        for (int k4 = 0; k4 < 32; ++k4) {
            float4 w = wr2[k4];
            a2 += h2[4 * k4] * w.x + h2[4 * k4 + 1] * w.y + h2[4 * k4 + 2] * w.z + h2[4 * k4 + 3] * w.w;
        }
        out[b * 5 + c] = a2;
    }
}

// ---------------- launch ----------------
extern "C" void kernel_launch(void* const* d_in, const int* in_sizes, int n_in,
                              void* d_out, int out_size, void* d_ws, size_t ws_size,
                              hipStream_t stream) {
    const int*   x   = (const int*)d_in[0];
    const float* w1  = (const float*)d_in[1];
    const float* b1  = (const float*)d_in[2];
    const float* w2  = (const float*)d_in[3];
    const float* b2  = (const float*)d_in[4];
    const float* w3  = (const float*)d_in[5];
    const float* b3  = (const float*)d_in[6];
    const float* wl1 = (const float*)d_in[7];
    const float* bl1 = (const float*)d_in[8];
    const float* wl2 = (const float*)d_in[9];
    const float* bl2 = (const float*)d_in[10];
    float* out = (float*)d_out;

    // workspace: all live ranges disjoint in time except as laid out; no aliasing needed.
    //   grid  @ 0        : 606000 B
    //   p1    @ 606000   : 384000 B
    //   p2    @ 990000   : 184320 B
    //   p3    @ 1174320  : 92160 B     (total 1.27 MB)
    char* ws = (char*)d_ws;
    float* grid = (float*)ws;
    float* p1   = (float*)(ws + 606000);
    float* p2   = (float*)(ws + 990000);
    float* p3   = (float*)(ws + 1174320);

    scatter_grid_kernel<<<Bb * 3, 256, 0, stream>>>(x, grid);
    conv1p1_kernel<<<Bb * 16, 384, 0, stream>>>(grid, w1, b1, p1);
    conv2p2_kernel<<<Bb * 18, 256, 0, stream>>>(p1, w2, b2, p2);
    conv3p3_kernel<<<Bb * 9, 256, 0, stream>>>(p2, w3, b3, p3);
    head_kernel<<<Bb, 128, 0, stream>>>(p3, wl1, bl1, wl2, bl2, out);
}